// Round 8
// baseline (1068.318 us; speedup 1.0000x reference)
//
#include <hip/hip_runtime.h>
#include <hip/hip_bf16.h>

#define N_ 8192
#define E_ 131072

typedef unsigned short u16;
typedef unsigned int u32;
typedef __attribute__((ext_vector_type(8))) short bf16x8;
typedef __attribute__((ext_vector_type(4))) float f32x4;

__device__ __forceinline__ float bf2f(u16 u){ return __uint_as_float(((u32)u)<<16); }
__device__ __forceinline__ u16 f2bf(float f){
  u32 u = __float_as_uint(f);
  u32 r = (u + 0x7fffu + ((u>>16)&1u)) >> 16;
  return (u16)r;
}
__device__ __forceinline__ float gelu_f(float x){ return 0.5f*x*(1.f+erff(x*0.70710678118654752f)); }

// XOR-swizzle: permute byte bits 4-6 keyed on bits >=7 (involution; 16B-chunk preserving)
template<int S1,int S2>
__device__ __forceinline__ u32 swz(u32 b){
  if (S1==0) return b;
  u32 k = b >> S1;
  if (S2) k ^= (b >> S2);
  return b ^ ((k & 7u) << 4);
}

// ---------------------------------------------------------------------------
// conv1 weight pack: f32 [co][ci*25+tap] -> bf16 [co][104] with kk = ci*32+tap
// ---------------------------------------------------------------------------
__global__ __launch_bounds__(256) void wpack1_k(const float* __restrict__ src,
    u16* __restrict__ dst)
{
  int e = blockIdx.x*256 + threadIdx.x;
  if (e < 3328){
    int co = e / 104, r = e - co*104;
    int ci = r >> 5, tap = r & 31;
    u16 v = 0;
    if (ci < 3 && tap < 25) v = f2bf(src[co*75 + ci*25 + tap]);
    dst[e] = v;
  }
}

// ---------------------------------------------------------------------------
// weight pack (conv2/3/4): f32 OIHW [co][ci][tap9] -> bf16 [tap][co][ci]
// ---------------------------------------------------------------------------
__global__ __launch_bounds__(256) void wpack_k(const float* __restrict__ src,
    u16* __restrict__ dst, int CO, int CI, int total)
{
  int e = blockIdx.x*256 + threadIdx.x;
  if (e < total){
    int tap = e / (CO*CI);
    int rem = e - tap*CO*CI;
    int co = rem / CI, ci = rem - co*CI;
    dst[e] = f2bf(src[((size_t)co*CI + ci)*9 + tap]);
  }
}

// ---------------------------------------------------------------------------
// conv1 MFMA: [N,3,32,32] f32 -> h1 NHWC [N][256][32] bf16, k5 s2 p2 +BN+GELU
// ---------------------------------------------------------------------------
__global__ __launch_bounds__(256) void conv1m_k(const float* __restrict__ patches,
    const u16* __restrict__ wp, const float* __restrict__ cb,
    const float* __restrict__ bng, const float* __restrict__ bnb,
    u16* __restrict__ h1)
{
  __shared__ __align__(16) u16 sbuf[4000 + 3328];
  int t = threadIdx.x;
  int img = blockIdx.x;

  for (int e=t; e<2000; e+=256) ((u32*)sbuf)[e] = 0;
  {
    const uint4* s4 = (const uint4*)wp;
    uint4* d4 = (uint4*)(sbuf + 4000);
    for (int e=t; e<416; e+=256) d4[e] = s4[e];
  }
  __syncthreads();
  {
    const float* src = patches + (size_t)img*3072;
    for (int e=t; e<3072; e+=256){
      int ci = e >> 10, rem = e & 1023, iy = rem >> 5, ix = rem & 31;
      sbuf[ci*1332 + (iy+2)*37 + (ix+2)] = f2bf(src[e]);
    }
  }
  __syncthreads();

  int lane = t & 63, wv = t >> 6;
  int lr = lane & 15, g = lane >> 4;

  int roff[8];
  #pragma unroll
  for (int j=0;j<8;++j){
    int tap = g*8 + j;
    int ty = (tap*13) >> 6;
    int tx = tap - ty*5;
    roff[j] = ty*74 + tx*2;
  }

  int pixb[4];
  #pragma unroll
  for (int mt=0;mt<4;++mt){
    int row = wv*64 + mt*16 + lr;
    int oy = row >> 4, ox = row & 15;
    pixb[mt] = oy*148 + ox*4;
  }

  f32x4 acc[4][2];
  #pragma unroll
  for (int mt=0;mt<4;++mt){
    acc[mt][0] = (f32x4){0.f,0.f,0.f,0.f};
    acc[mt][1] = (f32x4){0.f,0.f,0.f,0.f};
  }

  #pragma unroll
  for (int ks=0; ks<3; ++ks){
    bf16x8 bfr[2];
    #pragma unroll
    for (int nt=0;nt<2;++nt){
      u32 b = (u32)((nt*16+lr)*208 + ks*64 + g*16);
      bfr[nt] = *(const bf16x8*)((const char*)(sbuf+4000) + b);
    }
    #pragma unroll
    for (int mt=0;mt<4;++mt){
      union { bf16x8 v; u16 s[8]; } a;
      const char* base = (const char*)sbuf + ks*2664 + pixb[mt];
      #pragma unroll
      for (int j=0;j<8;++j) a.s[j] = *(const u16*)(base + roff[j]);
      acc[mt][0] = __builtin_amdgcn_mfma_f32_16x16x32_bf16(a.v, bfr[0], acc[mt][0], 0,0,0);
      acc[mt][1] = __builtin_amdgcn_mfma_f32_16x16x32_bf16(a.v, bfr[1], acc[mt][1], 0,0,0);
    }
  }

  #pragma unroll
  for (int nt=0;nt<2;++nt){
    int co = nt*16 + lr;
    float S = bng[co]*rsqrtf(1.f+1e-5f);
    float T = cb[co]*S + bnb[co];
    #pragma unroll
    for (int mt=0;mt<4;++mt){
      #pragma unroll
      for (int j=0;j<4;++j){
        int opix = wv*64 + mt*16 + g*4 + j;
        h1[(size_t)img*8192 + opix*32 + co] = f2bf(gelu_f(acc[mt][nt][j]*S + T));
      }
    }
  }
}

// ---------------------------------------------------------------------------
// MFMA implicit-GEMM 3x3 s2 p1 conv: NHWC bf16 in -> NHWC bf16 out (or pooled)
// A from swizzled LDS; B read directly from global (L1/L2-cached, no w_l,
// no per-tap barriers). Main K-loop is barrier-free.
// ---------------------------------------------------------------------------
template<int CI,int CO,int IH,int OH,int WAVES,int MT,int SA1,int SA2,int POOL>
__global__ __launch_bounds__(WAVES*64) void convm_k(const u16* __restrict__ hin,
    const u16* __restrict__ wp, const float* __restrict__ cb,
    const float* __restrict__ bng, const float* __restrict__ bnb,
    u16* __restrict__ hout, float* __restrict__ pooled)
{
  constexpr int OPIX = OH*OH, IPIX = IH*IH;
  constexpr int NT = CO/16, KS = CI/32;
  constexpr int ROWS = WAVES*MT*16;
  constexpr int IMG = ROWS/OPIX;
  constexpr int IMGB = IPIX*CI*2;
  constexpr int TH = WAVES*64;
  constexpr int OPSH = (OPIX==64)?6:((OPIX==16)?4:2);
  constexpr int OHSH = (OH==8)?3:((OH==4)?2:1);

  __shared__ u16 in_l[IMG*IPIX*CI];

  int t = threadIdx.x, blk = blockIdx.x;
  int lane = t & 63, wv = t >> 6;
  int lr = lane & 15, g = lane >> 4;

  {
    const uint4* src = (const uint4*)(hin + (size_t)blk*IMG*IPIX*CI);
    constexpr int CH = IMG*IPIX*CI/8;
    for (int e=t; e<CH; e+=TH){
      uint4 v = src[e];
      *(uint4*)((char*)in_l + swz<SA1,SA2>((u32)e*16u)) = v;
    }
  }
  __syncthreads();

  int oyv[MT], oxv[MT], ibv[MT];
  #pragma unroll
  for (int mt=0; mt<MT; ++mt){
    int rl = wv*(MT*16) + mt*16 + lr;
    int imgl = rl >> OPSH;
    int opix = rl & (OPIX-1);
    oyv[mt] = opix >> OHSH;
    oxv[mt] = opix & (OH-1);
    ibv[mt] = imgl*IMGB;
  }

  f32x4 acc[MT][NT];
  #pragma unroll
  for (int mt=0;mt<MT;++mt)
    #pragma unroll
    for (int nt=0;nt<NT;++nt) acc[mt][nt] = (f32x4){0.f,0.f,0.f,0.f};

  for (int tap=0; tap<9; ++tap){
    int ky = (tap<3)?0:((tap<6)?1:2);
    int kx = tap - ky*3;
    const u16* wt = wp + (size_t)tap*CO*CI;
    #pragma unroll
    for (int ks=0; ks<KS; ++ks){
      bf16x8 af[MT];
      #pragma unroll
      for (int mt=0; mt<MT; ++mt){
        int iy = 2*oyv[mt] - 1 + ky;
        int ix = 2*oxv[mt] - 1 + kx;
        bf16x8 a = {};
        if (iy>=0 && iy<IH && ix>=0 && ix<IH){
          u32 b = (u32)(ibv[mt] + (iy*IH+ix)*CI*2 + ks*64 + g*16);
          a = *(const bf16x8*)((const char*)in_l + swz<SA1,SA2>(b));
        }
        af[mt] = a;
      }
      #pragma unroll
      for (int nt=0; nt<NT; ++nt){
        bf16x8 bfr = *(const bf16x8*)(wt + (size_t)(nt*16+lr)*CI + ks*32 + g*8);
        #pragma unroll
        for (int mt=0; mt<MT; ++mt)
          acc[mt][nt] = __builtin_amdgcn_mfma_f32_16x16x32_bf16(af[mt], bfr, acc[mt][nt], 0, 0, 0);
      }
    }
  }

  if (!POOL){
    #pragma unroll
    for (int nt=0; nt<NT; ++nt){
      int co = nt*16 + lr;
      float S = bng[co]*rsqrtf(1.f+1e-5f);
      float T = cb[co]*S + bnb[co];
      #pragma unroll
      for (int mt=0; mt<MT; ++mt){
        #pragma unroll
        for (int j=0;j<4;++j){
          int rl = wv*(MT*16) + mt*16 + g*4 + j;
          int imgl = rl >> OPSH, opix = rl & (OPIX-1);
          float y = gelu_f(acc[mt][nt][j]*S + T);
          hout[((size_t)(blk*IMG + imgl)*OPIX + opix)*CO + co] = f2bf(y);
        }
      }
    }
  } else {
    // conv4 fused 2x2 mean-pool: rows g*4+j of this wave = image wv*4+g's 4 opix
    #pragma unroll
    for (int nt=0; nt<NT; ++nt){
      int co = nt*16 + lr;
      float S = bng[co]*rsqrtf(1.f+1e-5f);
      float T = cb[co]*S + bnb[co];
      float s = 0.f;
      #pragma unroll
      for (int j=0;j<4;++j) s += gelu_f(acc[0][nt][j]*S + T);
      int n = blk*IMG + wv*4 + g;
      pooled[(size_t)n*CO + co] = 0.25f*s;
    }
  }
}

// ---------------------------------------------------------------------------
// fused GEMM: C[8192,256] = A@W^T (+A2@W2^T) + bias (+gated bias2) (+coords)
// ---------------------------------------------------------------------------
template<int MODE>
__global__ __launch_bounds__(256) void gemm_k(const float* __restrict__ A, const float* __restrict__ W,
   const float* __restrict__ bias, int ldw,
   const float* __restrict__ A2, const float* __restrict__ W2, const float* __restrict__ bias2,
   const int* __restrict__ deg, const float* __restrict__ coords, const float* __restrict__ pjw,
   float* __restrict__ C)
{
  __shared__ float a_l[32*16];
  __shared__ float b_l[32*256];
  int t=threadIdx.x; int row0=blockIdx.x*16;
  int tm=t>>6, tn=t&63;
  float acc[4][4];
  #pragma unroll
  for (int i=0;i<4;++i)
    #pragma unroll
    for (int j=0;j<4;++j) acc[i][j]=0.f;
  const int passes = (MODE==2)?2:1;
  for (int ps2=0; ps2<passes; ++ps2){
    const float* Ap = ps2? A2:A; const float* Wp = ps2? W2:W; int ld = ps2?256:ldw;
    for (int k0=0;k0<256;k0+=32){
      {
        int e=t*2; int r=e>>5; int k=e&31;
        float2 v = *(const float2*)&Ap[(size_t)(row0+r)*256 + k0+k];
        a_l[k*16+r]=v.x; a_l[(k+1)*16+r]=v.y;
      }
      {
        const float* wr = &Wp[(size_t)t*ld + k0];
        #pragma unroll
        for (int kk=0;kk<32;kk+=2){ float2 v = *(const float2*)&wr[kk]; b_l[kk*256+t]=v.x; b_l[(kk+1)*256+t]=v.y; }
      }
      __syncthreads();
      #pragma unroll
      for (int k=0;k<32;++k){
        float4 av = *(const float4*)&a_l[k*16+tm*4];
        float4 bv = *(const float4*)&b_l[k*256+tn*4];
        float aa[4]={av.x,av.y,av.z,av.w};
        float bb[4]={bv.x,bv.y,bv.z,bv.w};
        #pragma unroll
        for (int i=0;i<4;++i)
          #pragma unroll
          for (int j=0;j<4;++j) acc[i][j]+=aa[i]*bb[j];
      }
      __syncthreads();
    }
  }
  float4 bv = *(const float4*)&bias[tn*4];
  float bias4[4]={bv.x,bv.y,bv.z,bv.w};
  float b24[4]={0.f,0.f,0.f,0.f};
  float cw0[4], cw1[4];
  if (MODE==2){
    float4 b2 = *(const float4*)&bias2[tn*4];
    b24[0]=b2.x; b24[1]=b2.y; b24[2]=b2.z; b24[3]=b2.w;
  }
  if (MODE==1){
    #pragma unroll
    for (int j=0;j<4;++j){ cw0[j]=pjw[(size_t)(tn*4+j)*258+256]; cw1[j]=pjw[(size_t)(tn*4+j)*258+257]; }
  }
  #pragma unroll
  for (int i=0;i<4;++i){
    int r = row0 + tm*4 + i;
    float g2 = 0.f, c0=0.f, c1=0.f;
    if (MODE==2) g2 = (deg[r]>0)?1.f:0.f;
    if (MODE==1){ c0 = coords[(size_t)r*2]*1e-4f; c1 = coords[(size_t)r*2+1]*1e-4f; }
    float4 o;
    float vals[4];
    #pragma unroll
    for (int j=0;j<4;++j){
      float v = acc[i][j] + bias4[j];
      if (MODE==2) v += g2*b24[j];
      if (MODE==1) v += c0*cw0[j] + c1*cw1[j];
      vals[j]=v;
    }
    o.x=vals[0]; o.y=vals[1]; o.z=vals[2]; o.w=vals[3];
    *(float4*)&C[(size_t)r*256 + tn*4] = o;
  }
}

// ---------------------------------------------------------------------------
// LayerNorm variants. MODE 0: out = gelu(LN(tin))  MODE 1: out = LN(x + gelu(tin))
// ---------------------------------------------------------------------------
template<int MODE>
__global__ __launch_bounds__(256) void ln_k(const float* __restrict__ xin, const float* __restrict__ tin,
  const float* __restrict__ g, const float* __restrict__ b, float* __restrict__ out)
{
  int row = blockIdx.x, t = threadIdx.x;
  size_t o = (size_t)row*256+t;
  float v;
  if (MODE==0) v = tin[o];
  else v = xin[o] + gelu_f(tin[o]);
  float s = v, sq = v*v;
  #pragma unroll
  for (int off=32; off>=1; off>>=1){ s += __shfl_xor(s,off); sq += __shfl_xor(sq,off); }
  __shared__ float red[8];
  int wv = t>>6;
  if ((t&63)==0){ red[wv*2]=s; red[wv*2+1]=sq; }
  __syncthreads();
  s = red[0]+red[2]+red[4]+red[6];
  sq = red[1]+red[3]+red[5]+red[7];
  float mu = s*(1.f/256.f);
  float var = sq*(1.f/256.f) - mu*mu;
  float rs = rsqrtf(var + 1e-5f);
  float y = (v-mu)*rs*g[t] + b[t];
  if (MODE==0) y = gelu_f(y);
  out[o] = y;
}

// ---------------------------------------------------------------------------
// CSR build + gather-mean
// ---------------------------------------------------------------------------
__global__ __launch_bounds__(256) void degcount_k(const int* __restrict__ dst, int* __restrict__ deg){
  int e = blockIdx.x*256+threadIdx.x;
  if (e<E_) atomicAdd(&deg[dst[e]],1);
}

__global__ __launch_bounds__(256) void scan_k(const int* __restrict__ deg, int* __restrict__ rowptr,
  float* __restrict__ invd)
{
  __shared__ int part[256];
  int t = threadIdx.x;
  int base = t*32; int run=0; int loc[32];
  #pragma unroll
  for (int i=0;i<32;++i){ loc[i]=run; run += deg[base+i]; }
  part[t]=run;
  __syncthreads();
  for (int off=1; off<256; off<<=1){
    int v = (t>=off)? part[t-off] : 0;
    __syncthreads();
    part[t]+=v;
    __syncthreads();
  }
  int pre = (t>0)? part[t-1] : 0;
  #pragma unroll
  for (int i=0;i<32;++i){
    rowptr[base+i] = pre + loc[i];
    int dv = deg[base+i];
    invd[base+i] = 1.f/fmaxf((float)dv,1.f);
  }
  if (t==255) rowptr[N_] = part[255];
}

__global__ __launch_bounds__(256) void fill_k(const int* __restrict__ src, const int* __restrict__ dst,
  const int* __restrict__ rowptr, int* __restrict__ cursor, int* __restrict__ colidx)
{
  int e = blockIdx.x*256+threadIdx.x;
  if (e<E_){
    int d = dst[e];
    int pos = rowptr[d] + atomicAdd(&cursor[d],1);
    colidx[pos] = src[e];
  }
}

__global__ __launch_bounds__(256) void gather_k(const float* __restrict__ x, const int* __restrict__ rowptr,
    const int* __restrict__ colidx, const float* __restrict__ invd, float* __restrict__ xbar)
{
  int d = blockIdx.x, t = threadIdx.x;
  int j0 = rowptr[d], j1 = rowptr[d+1];
  float s = 0.f;
  for (int j=j0;j<j1;++j){ int c = colidx[j]; s += x[(size_t)c*256+t]; }
  xbar[(size_t)d*256+t] = s*invd[d];
}

// ---------------------------------------------------------------------------
// heads: comp(8) / cmpo(16) / prog(32) from final x
// ---------------------------------------------------------------------------
__global__ __launch_bounds__(64) void heads_k(const float* __restrict__ x,
  const float* __restrict__ cw, const float* __restrict__ cbs,
  const float* __restrict__ mw, const float* __restrict__ mbs,
  const float* __restrict__ pw, const float* __restrict__ pbs,
  float* __restrict__ out)
{
  __shared__ float xr[256];
  int row = blockIdx.x, t = threadIdx.x;
  *(float4*)&xr[t*4] = *(const float4*)&x[(size_t)row*256 + t*4];
  __syncthreads();
  if (t>=56) return;
  const float* w; float bb; float* op;
  if (t<8){ w=&cw[t*256]; bb=cbs[t]; op = out + 2097152 + (size_t)row*8 + t; }
  else if (t<24){ int q=t-8; w=&mw[q*256]; bb=mbs[q]; op = out + 2162688 + (size_t)row*16 + q; }
  else { int q=t-24; w=&pw[q*256]; bb=pbs[q]; op = out + 2293760 + (size_t)row*32 + q; }
  float acc=0.f;
  #pragma unroll 8
  for (int k=0;k<256;k+=4){
    float4 xv=*(const float4*)&xr[k];
    float4 wv=*(const float4*)&w[k];
    acc += xv.x*wv.x + xv.y*wv.y + xv.z*wv.z + xv.w*wv.w;
  }
  *op = acc + bb;
}

// ---------------------------------------------------------------------------
// launch
// ---------------------------------------------------------------------------
extern "C" void kernel_launch(void* const* d_in, const int* in_sizes, int n_in,
                              void* d_out, int out_size, void* d_ws, size_t ws_size,
                              hipStream_t stream)
{
  const float* patches = (const float*)d_in[0];
  const float* coords  = (const float*)d_in[1];
  const int*   eidx    = (const int*)d_in[2];
  const float* c1w = (const float*)d_in[3];  const float* c1b = (const float*)d_in[4];
  const float* b1g = (const float*)d_in[5];  const float* b1b = (const float*)d_in[6];
  const float* c2w = (const float*)d_in[7];  const float* c2b = (const float*)d_in[8];
  const float* b2g = (const float*)d_in[9];  const float* b2b = (const float*)d_in[10];
  const float* c3w = (const float*)d_in[11]; const float* c3b = (const float*)d_in[12];
  const float* b3g = (const float*)d_in[13]; const float* b3b = (const float*)d_in[14];
  const float* c4w = (const float*)d_in[15]; const float* c4b = (const float*)d_in[16];
  const float* b4g = (const float*)d_in[17]; const float* b4b = (const float*)d_in[18];
  const float* encw = (const float*)d_in[19]; const float* encb = (const float*)d_in[20];
  const float* pjw  = (const float*)d_in[21]; const float* pjb  = (const float*)d_in[22];
  const float* plng = (const float*)d_in[23]; const float* plnb = (const float*)d_in[24];
  const float* msgw = (const float*)d_in[25]; const float* msgb = (const float*)d_in[26];
  const float* spw  = (const float*)d_in[27]; const float* spb  = (const float*)d_in[28];
  const float* lng  = (const float*)d_in[29]; const float* lnb  = (const float*)d_in[30];
  const float* compw = (const float*)d_in[31]; const float* compb = (const float*)d_in[32];
  const float* cmpow = (const float*)d_in[33]; const float* cmpob = (const float*)d_in[34];
  const float* progw = (const float*)d_in[35]; const float* progb = (const float*)d_in[36];
  float* out = (float*)d_out;
  char* ws = (char*)d_ws;

  const size_t OFF_H1   = 0;                    // 134217728 bytes (bf16 NHWC)
  const size_t OFF_H2   = 134217728;            // 67108864 (NHWC)
  const size_t OFF_H3   = 201326592;            // 33554432 (NHWC)
  const size_t OFF_POOL = 234881024;            // 8388608
  const size_t OFF_IMGF = 243269632;            // 8388608
  const size_t OFF_TBUF = 251658240;            // 8388608
  const size_t OFF_XA   = 260046848;            // 8388608
  const size_t OFF_XB   = 268435456;            // 8388608
  const size_t OFF_XBAR = 276824064;            // 8388608
  const size_t OFF_DEG  = 285212672;            // 32768
  const size_t OFF_ROWP = 285245440;            // 65536
  const size_t OFF_CURS = 285310976;            // 32768
  const size_t OFF_COL  = 285343744;            // 524288
  const size_t OFF_INVD = 285868032;            // 32768
  const size_t OFF_WP4  = OFF_TBUF;             // 589824 (bf16)
  const size_t OFF_WP3  = OFF_TBUF + 589824;    // 147456
  const size_t OFF_WP2  = OFF_TBUF + 737280;    // 36864
  const size_t OFF_WP1  = OFF_TBUF + 774144;    // 6656 (bf16 [32][104])

  u16* h1 = (u16*)(ws+OFF_H1);
  u16* h2 = (u16*)(ws+OFF_H2);
  u16* h3 = (u16*)(ws+OFF_H3);
  float* pooled = (float*)(ws+OFF_POOL);
  float* imgf = (float*)(ws+OFF_IMGF);
  float* tbuf = (float*)(ws+OFF_TBUF);
  float* xa = (float*)(ws+OFF_XA);
  float* xb = (float*)(ws+OFF_XB);
  float* xbar = (float*)(ws+OFF_XBAR);
  int* deg = (int*)(ws+OFF_DEG);
  int* rowp = (int*)(ws+OFF_ROWP);
  int* curs = (int*)(ws+OFF_CURS);
  int* col = (int*)(ws+OFF_COL);
  float* invd = (float*)(ws+OFF_INVD);
  u16* wp1 = (u16*)(ws+OFF_WP1);
  u16* wp2 = (u16*)(ws+OFF_WP2);
  u16* wp3 = (u16*)(ws+OFF_WP3);
  u16* wp4 = (u16*)(ws+OFF_WP4);

  hipMemsetAsync(deg, 0, 32768, stream);
  hipMemsetAsync(curs, 0, 32768, stream);

  wpack1_k<<<13,256,0,stream>>>(c1w, wp1);
  wpack_k<<<(18432+255)/256,256,0,stream>>>(c2w, wp2, 64, 32, 18432);
  wpack_k<<<(73728+255)/256,256,0,stream>>>(c3w, wp3, 128, 64, 73728);
  wpack_k<<<(294912+255)/256,256,0,stream>>>(c4w, wp4, 256, 128, 294912);

  conv1m_k<<<8192,256,0,stream>>>(patches, wp1, c1b, b1g, b1b, h1);
  // conv2: CI=32 CO=64 IH=16 OH=8, 8 waves x MT2 -> 4 img/block, LDS 64KB (in only)
  convm_k<32,64,16,8,8,2,7,0,0><<<2048,512,0,stream>>>(h1, wp2, c2b, b2g, b2b, h2, nullptr);
  // conv3: CI=64 CO=128 IH=8 OH=4, 4 waves x MT2 -> 8 img/block, LDS 64KB
  convm_k<64,128,8,4,4,2,8,11,0><<<1024,256,0,stream>>>(h2, wp3, c3b, b3g, b3b, h3, nullptr);
  // conv4: CI=128 CO=256 IH=4 OH=2, 8 waves x MT1 -> 32 img/block, LDS 128KB, fused pool
  convm_k<128,256,4,2,8,1,9,12,1><<<256,512,0,stream>>>(h3, wp4, c4b, b4g, b4b, nullptr, pooled);

  gemm_k<0><<<512,256,0,stream>>>(pooled, encw, encb, 256, nullptr,nullptr,nullptr,nullptr,nullptr,nullptr, imgf);
  gemm_k<1><<<512,256,0,stream>>>(imgf, pjw, pjb, 258, nullptr,nullptr,nullptr,nullptr, coords, pjw, tbuf);
  ln_k<0><<<8192,256,0,stream>>>(tbuf, tbuf, plng, plnb, xa);

  degcount_k<<<512,256,0,stream>>>(eidx+E_, deg);
  scan_k<<<1,256,0,stream>>>(deg, rowp, invd);
  fill_k<<<512,256,0,stream>>>(eidx, eidx+E_, rowp, curs, col);

  float* xcur = xa;
  for (int i=0;i<4;++i){
    gather_k<<<8192,256,0,stream>>>(xcur, rowp, col, invd, xbar);
    gemm_k<2><<<512,256,0,stream>>>(xcur, spw+(size_t)i*65536, spb+(size_t)i*256, 256,
                                    xbar, msgw+(size_t)i*65536, msgb+(size_t)i*256,
                                    deg, nullptr, nullptr, tbuf);
    float* xnext = (i==3)? out : ((i&1)? xa : xb);
    ln_k<1><<<8192,256,0,stream>>>(xcur, tbuf, lng+(size_t)i*256, lnb+(size_t)i*256, xnext);
    xcur = xnext;
  }
  heads_k<<<8192,64,0,stream>>>(out, compw, compb, cmpow, cmpob, progw, progb, out);
}

// Round 9
// 947.460 us; speedup vs baseline: 1.1276x; 1.1276x over previous
//
#include <hip/hip_runtime.h>
#include <hip/hip_bf16.h>

#define N_ 8192
#define E_ 131072

typedef unsigned short u16;
typedef unsigned int u32;
typedef __attribute__((ext_vector_type(8))) short bf16x8;
typedef __attribute__((ext_vector_type(4))) float f32x4;

__device__ __forceinline__ float bf2f(u16 u){ return __uint_as_float(((u32)u)<<16); }
__device__ __forceinline__ u16 f2bf(float f){
  u32 u = __float_as_uint(f);
  u32 r = (u + 0x7fffu + ((u>>16)&1u)) >> 16;
  return (u16)r;
}
__device__ __forceinline__ float gelu_f(float x){ return 0.5f*x*(1.f+erff(x*0.70710678118654752f)); }

// XOR-swizzle: permute byte bits 4-6 keyed on bits >= S1 (involution; 16B-preserving)
template<int S1,int S2>
__device__ __forceinline__ u32 swz(u32 b){
  if (S1==0) return b;
  u32 k = b >> S1;
  if (S2) k ^= (b >> S2);
  return b ^ ((k & 7u) << 4);
}

// ---------------------------------------------------------------------------
// conv1 weight pack: f32 [co][ci*25+tap] -> bf16 [co][104] with kk = ci*32+tap
// ---------------------------------------------------------------------------
__global__ __launch_bounds__(256) void wpack1_k(const float* __restrict__ src,
    u16* __restrict__ dst)
{
  int e = blockIdx.x*256 + threadIdx.x;
  if (e < 3328){
    int co = e / 104, r = e - co*104;
    int ci = r >> 5, tap = r & 31;
    u16 v = 0;
    if (ci < 3 && tap < 25) v = f2bf(src[co*75 + ci*25 + tap]);
    dst[e] = v;
  }
}

// ---------------------------------------------------------------------------
// weight pack (conv2/3/4): f32 OIHW [co][ci][tap9] -> bf16 [tap][co][ci]
// ---------------------------------------------------------------------------
__global__ __launch_bounds__(256) void wpack_k(const float* __restrict__ src,
    u16* __restrict__ dst, int CO, int CI, int total)
{
  int e = blockIdx.x*256 + threadIdx.x;
  if (e < total){
    int tap = e / (CO*CI);
    int rem = e - tap*CO*CI;
    int co = rem / CI, ci = rem - co*CI;
    dst[e] = f2bf(src[((size_t)co*CI + ci)*9 + tap]);
  }
}

// ---------------------------------------------------------------------------
// generic GEMM-weight pack: f32 [CO][ld] -> bf16 [CO][K]  (K=256)
// ---------------------------------------------------------------------------
__global__ __launch_bounds__(256) void wpackg_k(const float* __restrict__ src,
    u16* __restrict__ dst, int ld, int total)
{
  int e = blockIdx.x*256 + threadIdx.x;
  if (e < total){
    int co = e >> 8, k = e & 255;
    dst[e] = f2bf(src[(size_t)co*ld + k]);
  }
}

// ---------------------------------------------------------------------------
// conv1 MFMA: [N,3,32,32] f32 -> h1 NHWC [N][256][32] bf16, k5 s2 p2 +BN+GELU
// ---------------------------------------------------------------------------
__global__ __launch_bounds__(256) void conv1m_k(const float* __restrict__ patches,
    const u16* __restrict__ wp, const float* __restrict__ cb,
    const float* __restrict__ bng, const float* __restrict__ bnb,
    u16* __restrict__ h1)
{
  __shared__ __align__(16) u16 sbuf[4000 + 3328];
  int t = threadIdx.x;
  int img = blockIdx.x;

  for (int e=t; e<2000; e+=256) ((u32*)sbuf)[e] = 0;
  {
    const uint4* s4 = (const uint4*)wp;
    uint4* d4 = (uint4*)(sbuf + 4000);
    for (int e=t; e<416; e+=256) d4[e] = s4[e];
  }
  __syncthreads();
  {
    const float* src = patches + (size_t)img*3072;
    for (int e=t; e<3072; e+=256){
      int ci = e >> 10, rem = e & 1023, iy = rem >> 5, ix = rem & 31;
      sbuf[ci*1332 + (iy+2)*37 + (ix+2)] = f2bf(src[e]);
    }
  }
  __syncthreads();

  int lane = t & 63, wv = t >> 6;
  int lr = lane & 15, g = lane >> 4;

  int roff[8];
  #pragma unroll
  for (int j=0;j<8;++j){
    int tap = g*8 + j;
    int ty = (tap*13) >> 6;
    int tx = tap - ty*5;
    roff[j] = ty*74 + tx*2;
  }

  int pixb[4];
  #pragma unroll
  for (int mt=0;mt<4;++mt){
    int row = wv*64 + mt*16 + lr;
    int oy = row >> 4, ox = row & 15;
    pixb[mt] = oy*148 + ox*4;
  }

  f32x4 acc[4][2];
  #pragma unroll
  for (int mt=0;mt<4;++mt){
    acc[mt][0] = (f32x4){0.f,0.f,0.f,0.f};
    acc[mt][1] = (f32x4){0.f,0.f,0.f,0.f};
  }

  #pragma unroll
  for (int ks=0; ks<3; ++ks){
    bf16x8 bfr[2];
    #pragma unroll
    for (int nt=0;nt<2;++nt){
      u32 b = (u32)((nt*16+lr)*208 + ks*64 + g*16);
      bfr[nt] = *(const bf16x8*)((const char*)(sbuf+4000) + b);
    }
    #pragma unroll
    for (int mt=0;mt<4;++mt){
      union { bf16x8 v; u16 s[8]; } a;
      const char* base = (const char*)sbuf + ks*2664 + pixb[mt];
      #pragma unroll
      for (int j=0;j<8;++j) a.s[j] = *(const u16*)(base + roff[j]);
      acc[mt][0] = __builtin_amdgcn_mfma_f32_16x16x32_bf16(a.v, bfr[0], acc[mt][0], 0,0,0);
      acc[mt][1] = __builtin_amdgcn_mfma_f32_16x16x32_bf16(a.v, bfr[1], acc[mt][1], 0,0,0);
    }
  }

  #pragma unroll
  for (int nt=0;nt<2;++nt){
    int co = nt*16 + lr;
    float S = bng[co]*rsqrtf(1.f+1e-5f);
    float T = cb[co]*S + bnb[co];
    #pragma unroll
    for (int mt=0;mt<4;++mt){
      #pragma unroll
      for (int j=0;j<4;++j){
        int opix = wv*64 + mt*16 + g*4 + j;
        h1[(size_t)img*8192 + opix*32 + co] = f2bf(gelu_f(acc[mt][nt][j]*S + T));
      }
    }
  }
}

// ---------------------------------------------------------------------------
// MFMA implicit-GEMM 3x3 s2 p1 conv, wave-N-split (NW n-groups).
// A from swizzled LDS; B from global (L2-hot). NT/wave small -> B fits VGPRs.
// ---------------------------------------------------------------------------
template<int CI,int CO,int IH,int OH,int WAVES,int NW,int MT,int SA1,int SA2,int POOL>
__global__ __launch_bounds__(WAVES*64) void convm_k(const u16* __restrict__ hin,
    const u16* __restrict__ wp, const float* __restrict__ cb,
    const float* __restrict__ bng, const float* __restrict__ bnb,
    u16* __restrict__ hout, u16* __restrict__ pooled)
{
  constexpr int OPIX = OH*OH, IPIX = IH*IH;
  constexpr int NT = CO/16/NW, KS = CI/32;
  constexpr int MG = WAVES/NW;
  constexpr int ROWS = MG*MT*16;
  constexpr int IMG = ROWS/OPIX;
  constexpr int IMGB = IPIX*CI*2;
  constexpr int TH = WAVES*64;
  constexpr int OPSH = (OPIX==64)?6:((OPIX==16)?4:2);
  constexpr int OHSH = (OH==8)?3:((OH==4)?2:1);
  constexpr int NWS = (NW==1)?0:((NW==2)?1:2);

  __shared__ u16 in_l[IMG*IPIX*CI];

  int t = threadIdx.x, blk = blockIdx.x;
  int lane = t & 63, wv = t >> 6;
  int lr = lane & 15, g = lane >> 4;
  int mg = wv >> NWS, nw = wv & (NW-1);
  int ncb = nw*(NT*16);

  {
    const uint4* src = (const uint4*)(hin + (size_t)blk*IMG*IPIX*CI);
    constexpr int CH = IMG*IPIX*CI/8;
    for (int e=t; e<CH; e+=TH){
      uint4 v = src[e];
      *(uint4*)((char*)in_l + swz<SA1,SA2>((u32)e*16u)) = v;
    }
  }
  __syncthreads();

  int oyv[MT], oxv[MT], ibv[MT];
  #pragma unroll
  for (int mt=0; mt<MT; ++mt){
    int rl = mg*(MT*16) + mt*16 + lr;
    int imgl = rl >> OPSH;
    int opix = rl & (OPIX-1);
    oyv[mt] = opix >> OHSH;
    oxv[mt] = opix & (OH-1);
    ibv[mt] = imgl*IMGB;
  }

  f32x4 acc[MT][NT];
  #pragma unroll
  for (int mt=0;mt<MT;++mt)
    #pragma unroll
    for (int nt=0;nt<NT;++nt) acc[mt][nt] = (f32x4){0.f,0.f,0.f,0.f};

  for (int tap=0; tap<9; ++tap){
    int ky = (tap<3)?0:((tap<6)?1:2);
    int kx = tap - ky*3;
    const u16* wt = wp + (size_t)tap*CO*CI;
    #pragma unroll
    for (int ks=0; ks<KS; ++ks){
      bf16x8 af[MT];
      #pragma unroll
      for (int mt=0; mt<MT; ++mt){
        int iy = 2*oyv[mt] - 1 + ky;
        int ix = 2*oxv[mt] - 1 + kx;
        bf16x8 a = {};
        if (iy>=0 && iy<IH && ix>=0 && ix<IH){
          u32 b = (u32)(ibv[mt] + (iy*IH+ix)*CI*2 + ks*64 + g*16);
          a = *(const bf16x8*)((const char*)in_l + swz<SA1,SA2>(b));
        }
        af[mt] = a;
      }
      #pragma unroll
      for (int nt=0; nt<NT; ++nt){
        bf16x8 bfr = *(const bf16x8*)(wt + (size_t)(ncb + nt*16+lr)*CI + ks*32 + g*8);
        #pragma unroll
        for (int mt=0; mt<MT; ++mt)
          acc[mt][nt] = __builtin_amdgcn_mfma_f32_16x16x32_bf16(af[mt], bfr, acc[mt][nt], 0, 0, 0);
      }
    }
  }

  if (!POOL){
    #pragma unroll
    for (int nt=0; nt<NT; ++nt){
      int co = ncb + nt*16 + lr;
      float S = bng[co]*rsqrtf(1.f+1e-5f);
      float T = cb[co]*S + bnb[co];
      #pragma unroll
      for (int mt=0; mt<MT; ++mt){
        #pragma unroll
        for (int j=0;j<4;++j){
          int rl = mg*(MT*16) + mt*16 + g*4 + j;
          int imgl = rl >> OPSH, opix = rl & (OPIX-1);
          float y = gelu_f(acc[mt][nt][j]*S + T);
          hout[((size_t)(blk*IMG + imgl)*OPIX + opix)*CO + co] = f2bf(y);
        }
      }
    }
  } else {
    // fused 2x2 mean-pool (OPIX=4): each mt-tile's lane-group g = one image
    #pragma unroll
    for (int nt=0; nt<NT; ++nt){
      int co = ncb + nt*16 + lr;
      float S = bng[co]*rsqrtf(1.f+1e-5f);
      float T = cb[co]*S + bnb[co];
      #pragma unroll
      for (int mt=0; mt<MT; ++mt){
        float s = 0.f;
        #pragma unroll
        for (int j=0;j<4;++j) s += gelu_f(acc[mt][nt][j]*S + T);
        int n = blk*IMG + mg*(MT*4) + mt*4 + g;
        pooled[(size_t)n*CO + co] = f2bf(0.25f*s);
      }
    }
  }
}

// ---------------------------------------------------------------------------
// MFMA GEMM: C[8192,256] = A@W^T (+A2@W2^T) + bias (+gated bias2 / +coords)
// A bf16 [8192][256] staged in swizzled LDS (32KB, once per pass, barrier-free
// K-loop); B bf16 [256][256] from global (L2-hot). Block = 64x64 tile, 4 waves.
// MODE 0: single K, bf16 out   MODE 1: +coords epilogue, f32 out   MODE 2: dual
// ---------------------------------------------------------------------------
template<int MODE>
__global__ __launch_bounds__(256) void gemm_m(
    const u16* __restrict__ A1, const u16* __restrict__ W1, const float* __restrict__ b1,
    const u16* __restrict__ A2, const u16* __restrict__ W2, const float* __restrict__ b2,
    const int* __restrict__ deg, const float* __restrict__ coords, const float* __restrict__ pjw,
    float* __restrict__ Cf, u16* __restrict__ Ch)
{
  __shared__ __align__(16) u16 a_l[64*256];
  int t=threadIdx.x, lane=t&63, w=t>>6, lr=lane&15, g=lane>>4;
  int m0 = blockIdx.x*64, n0 = blockIdx.y*64;

  f32x4 acc[4];
  #pragma unroll
  for (int nt=0;nt<4;++nt) acc[nt] = (f32x4){0.f,0.f,0.f,0.f};

  const int passes = (MODE==2)?2:1;
  for (int ps=0; ps<passes; ++ps){
    const u16* Ap = ps? A2:A1;
    const u16* Wp = ps? W2:W1;
    __syncthreads();
    for (int e=t; e<2048; e+=256){
      u32 b = (u32)e*16u;
      uint4 v = *(const uint4*)(Ap + (size_t)(m0 + (e>>5))*256 + (e&31)*8);
      *(uint4*)((char*)a_l + (b ^ (((b>>9)&7u)<<4))) = v;
    }
    __syncthreads();
    #pragma unroll
    for (int ks=0; ks<8; ++ks){
      u32 ab = (u32)(w*16+lr)*512 + (u32)ks*64 + (u32)g*16;
      bf16x8 af = *(const bf16x8*)((const char*)a_l + (ab ^ (((ab>>9)&7u)<<4)));
      #pragma unroll
      for (int nt=0; nt<4; ++nt){
        bf16x8 bfv = *(const bf16x8*)(Wp + (size_t)(n0+nt*16+lr)*256 + ks*32 + g*8);
        acc[nt] = __builtin_amdgcn_mfma_f32_16x16x32_bf16(af, bfv, acc[nt], 0,0,0);
      }
    }
  }

  int row_base = m0 + w*16 + g*4;
  #pragma unroll
  for (int nt=0; nt<4; ++nt){
    int col = n0 + nt*16 + lr;
    float bb = b1[col];
    float b2v = 0.f, cw0 = 0.f, cw1 = 0.f;
    if (MODE==2) b2v = b2[col];
    if (MODE==1){ cw0 = pjw[(size_t)col*258+256]; cw1 = pjw[(size_t)col*258+257]; }
    #pragma unroll
    for (int j=0;j<4;++j){
      int r = row_base + j;
      float v = acc[nt][j] + bb;
      if (MODE==2) v += (deg[r]>0)? b2v : 0.f;
      if (MODE==1) v += coords[(size_t)r*2]*1e-4f*cw0 + coords[(size_t)r*2+1]*1e-4f*cw1;
      if (MODE==0) Ch[(size_t)r*256 + col] = f2bf(v);
      else         Cf[(size_t)r*256 + col] = v;
    }
  }
}

// ---------------------------------------------------------------------------
// LayerNorm. MODE 0: out = gelu(LN(tin))  MODE 1: out = LN(x + gelu(tin))
// also emits bf16 copy (GEMM A-operand)
// ---------------------------------------------------------------------------
template<int MODE>
__global__ __launch_bounds__(256) void ln_k(const float* __restrict__ xin, const float* __restrict__ tin,
  const float* __restrict__ g, const float* __restrict__ b, float* __restrict__ out,
  u16* __restrict__ houtb)
{
  int row = blockIdx.x, t = threadIdx.x;
  size_t o = (size_t)row*256+t;
  float v;
  if (MODE==0) v = tin[o];
  else v = xin[o] + gelu_f(tin[o]);
  float s = v, sq = v*v;
  #pragma unroll
  for (int off=32; off>=1; off>>=1){ s += __shfl_xor(s,off); sq += __shfl_xor(sq,off); }
  __shared__ float red[8];
  int wv = t>>6;
  if ((t&63)==0){ red[wv*2]=s; red[wv*2+1]=sq; }
  __syncthreads();
  s = red[0]+red[2]+red[4]+red[6];
  sq = red[1]+red[3]+red[5]+red[7];
  float mu = s*(1.f/256.f);
  float var = sq*(1.f/256.f) - mu*mu;
  float rs = rsqrtf(var + 1e-5f);
  float y = (v-mu)*rs*g[t] + b[t];
  if (MODE==0) y = gelu_f(y);
  out[o] = y;
  houtb[o] = f2bf(y);
}

// ---------------------------------------------------------------------------
// CSR build + gather-mean (writes bf16 xbar)
// ---------------------------------------------------------------------------
__global__ __launch_bounds__(256) void degcount_k(const int* __restrict__ dst, int* __restrict__ deg){
  int e = blockIdx.x*256+threadIdx.x;
  if (e<E_) atomicAdd(&deg[dst[e]],1);
}

__global__ __launch_bounds__(256) void scan_k(const int* __restrict__ deg, int* __restrict__ rowptr,
  float* __restrict__ invd)
{
  __shared__ int part[256];
  int t = threadIdx.x;
  int base = t*32; int run=0; int loc[32];
  #pragma unroll
  for (int i=0;i<32;++i){ loc[i]=run; run += deg[base+i]; }
  part[t]=run;
  __syncthreads();
  for (int off=1; off<256; off<<=1){
    int v = (t>=off)? part[t-off] : 0;
    __syncthreads();
    part[t]+=v;
    __syncthreads();
  }
  int pre = (t>0)? part[t-1] : 0;
  #pragma unroll
  for (int i=0;i<32;++i){
    rowptr[base+i] = pre + loc[i];
    int dv = deg[base+i];
    invd[base+i] = 1.f/fmaxf((float)dv,1.f);
  }
  if (t==255) rowptr[N_] = part[255];
}

__global__ __launch_bounds__(256) void fill_k(const int* __restrict__ src, const int* __restrict__ dst,
  const int* __restrict__ rowptr, int* __restrict__ cursor, int* __restrict__ colidx)
{
  int e = blockIdx.x*256+threadIdx.x;
  if (e<E_){
    int d = dst[e];
    int pos = rowptr[d] + atomicAdd(&cursor[d],1);
    colidx[pos] = src[e];
  }
}

__global__ __launch_bounds__(256) void gather_k(const float* __restrict__ x, const int* __restrict__ rowptr,
    const int* __restrict__ colidx, const float* __restrict__ invd, u16* __restrict__ xbarh)
{
  int d = blockIdx.x, t = threadIdx.x;
  int j0 = rowptr[d], j1 = rowptr[d+1];
  float s = 0.f;
  for (int j=j0;j<j1;++j){ int c = colidx[j]; s += x[(size_t)c*256+t]; }
  xbarh[(size_t)d*256+t] = f2bf(s*invd[d]);
}

// ---------------------------------------------------------------------------
// heads: comp(8) / cmpo(16) / prog(32) from final x
// ---------------------------------------------------------------------------
__global__ __launch_bounds__(64) void heads_k(const float* __restrict__ x,
  const float* __restrict__ cw, const float* __restrict__ cbs,
  const float* __restrict__ mw, const float* __restrict__ mbs,
  const float* __restrict__ pw, const float* __restrict__ pbs,
  float* __restrict__ out)
{
  __shared__ float xr[256];
  int row = blockIdx.x, t = threadIdx.x;
  *(float4*)&xr[t*4] = *(const float4*)&x[(size_t)row*256 + t*4];
  __syncthreads();
  if (t>=56) return;
  const float* w; float bb; float* op;
  if (t<8){ w=&cw[t*256]; bb=cbs[t]; op = out + 2097152 + (size_t)row*8 + t; }
  else if (t<24){ int q=t-8; w=&mw[q*256]; bb=mbs[q]; op = out + 2162688 + (size_t)row*16 + q; }
  else { int q=t-24; w=&pw[q*256]; bb=pbs[q]; op = out + 2293760 + (size_t)row*32 + q; }
  float acc=0.f;
  #pragma unroll 8
  for (int k=0;k<256;k+=4){
    float4 xv=*(const float4*)&xr[k];
    float4 wv=*(const float4*)&w[k];
    acc += xv.x*wv.x + xv.y*wv.y + xv.z*wv.z + xv.w*wv.w;
  }
  *op = acc + bb;
}

// ---------------------------------------------------------------------------
// launch
// ---------------------------------------------------------------------------
extern "C" void kernel_launch(void* const* d_in, const int* in_sizes, int n_in,
                              void* d_out, int out_size, void* d_ws, size_t ws_size,
                              hipStream_t stream)
{
  const float* patches = (const float*)d_in[0];
  const float* coords  = (const float*)d_in[1];
  const int*   eidx    = (const int*)d_in[2];
  const float* c1w = (const float*)d_in[3];  const float* c1b = (const float*)d_in[4];
  const float* b1g = (const float*)d_in[5];  const float* b1b = (const float*)d_in[6];
  const float* c2w = (const float*)d_in[7];  const float* c2b = (const float*)d_in[8];
  const float* b2g = (const float*)d_in[9];  const float* b2b = (const float*)d_in[10];
  const float* c3w = (const float*)d_in[11]; const float* c3b = (const float*)d_in[12];
  const float* b3g = (const float*)d_in[13]; const float* b3b = (const float*)d_in[14];
  const float* c4w = (const float*)d_in[15]; const float* c4b = (const float*)d_in[16];
  const float* b4g = (const float*)d_in[17]; const float* b4b = (const float*)d_in[18];
  const float* encw = (const float*)d_in[19]; const float* encb = (const float*)d_in[20];
  const float* pjw  = (const float*)d_in[21]; const float* pjb  = (const float*)d_in[22];
  const float* plng = (const float*)d_in[23]; const float* plnb = (const float*)d_in[24];
  const float* msgw = (const float*)d_in[25]; const float* msgb = (const float*)d_in[26];
  const float* spw  = (const float*)d_in[27]; const float* spb  = (const float*)d_in[28];
  const float* lng  = (const float*)d_in[29]; const float* lnb  = (const float*)d_in[30];
  const float* compw = (const float*)d_in[31]; const float* compb = (const float*)d_in[32];
  const float* cmpow = (const float*)d_in[33]; const float* cmpob = (const float*)d_in[34];
  const float* progw = (const float*)d_in[35]; const float* progb = (const float*)d_in[36];
  float* out = (float*)d_out;
  char* ws = (char*)d_ws;

  const size_t OFF_H1   = 0;                    // 134217728 (bf16 NHWC); reused later
  const size_t OFF_H2   = 134217728;            // 67108864 (NHWC)
  const size_t OFF_H3   = 201326592;            // 33554432 (NHWC)
  const size_t OFF_POOL = 234881024;            // pooled bf16 4MB + gemm wpacks
  const size_t OFF_IMGF = 243269632;            // imgf bf16 4MB + graph wpacks
  const size_t OFF_TBUF = 251658240;            // f32 C buffer 8MB (+conv wpacks early)
  const size_t OFF_XA   = 260046848;            // 8388608
  const size_t OFF_XB   = 268435456;            // 8388608
  const size_t OFF_DEG  = 285212672;            // 32768
  const size_t OFF_ROWP = 285245440;            // 65536
  const size_t OFF_CURS = 285310976;            // 32768
  const size_t OFF_COL  = 285343744;            // 524288
  const size_t OFF_INVD = 285868032;            // 32768
  // conv weight packs: in TBUF window (dead before proj gemm writes tbuf)
  const size_t OFF_WP4  = OFF_TBUF;             // 589824
  const size_t OFF_WP3  = OFF_TBUF + 589824;    // 147456
  const size_t OFF_WP2  = OFF_TBUF + 737280;    // 36864
  const size_t OFF_WP1  = OFF_TBUF + 774144;    // 6656
  // gemm weight packs (persist all launch): upper halves of POOL/IMGF windows
  const size_t OFF_ENCH = OFF_POOL + 4194304;   // 131072
  const size_t OFF_PJH  = OFF_POOL + 4325376;   // 131072
  const size_t OFF_SPH  = OFF_IMGF + 4194304;   // 524288
  const size_t OFF_MSGH = OFF_IMGF + 4718592;   // 524288
  // bf16 activations: reuse H1 window (dead after conv2)
  const size_t OFF_XH   = OFF_H1;               // 4194304
  const size_t OFF_XBH  = OFF_H1 + 4194304;     // 4194304

  u16* h1 = (u16*)(ws+OFF_H1);
  u16* h2 = (u16*)(ws+OFF_H2);
  u16* h3 = (u16*)(ws+OFF_H3);
  u16* pooled = (u16*)(ws+OFF_POOL);
  u16* imgf_h = (u16*)(ws+OFF_IMGF);
  float* tbuf = (float*)(ws+OFF_TBUF);
  float* xa = (float*)(ws+OFF_XA);
  float* xb = (float*)(ws+OFF_XB);
  int* deg = (int*)(ws+OFF_DEG);
  int* rowp = (int*)(ws+OFF_ROWP);
  int* curs = (int*)(ws+OFF_CURS);
  int* col = (int*)(ws+OFF_COL);
  float* invd = (float*)(ws+OFF_INVD);
  u16* wp1 = (u16*)(ws+OFF_WP1);
  u16* wp2 = (u16*)(ws+OFF_WP2);
  u16* wp3 = (u16*)(ws+OFF_WP3);
  u16* wp4 = (u16*)(ws+OFF_WP4);
  u16* encw_h = (u16*)(ws+OFF_ENCH);
  u16* pjw_h  = (u16*)(ws+OFF_PJH);
  u16* spw_h  = (u16*)(ws+OFF_SPH);
  u16* msgw_h = (u16*)(ws+OFF_MSGH);
  u16* xh     = (u16*)(ws+OFF_XH);
  u16* xbarh  = (u16*)(ws+OFF_XBH);

  hipMemsetAsync(deg, 0, 32768, stream);
  hipMemsetAsync(curs, 0, 32768, stream);

  wpack1_k<<<13,256,0,stream>>>(c1w, wp1);
  wpack_k<<<72,256,0,stream>>>(c2w, wp2, 64, 32, 18432);
  wpack_k<<<288,256,0,stream>>>(c3w, wp3, 128, 64, 73728);
  wpack_k<<<1152,256,0,stream>>>(c4w, wp4, 256, 128, 294912);
  wpackg_k<<<256,256,0,stream>>>(encw, encw_h, 256, 65536);
  wpackg_k<<<256,256,0,stream>>>(pjw,  pjw_h,  258, 65536);
  wpackg_k<<<1024,256,0,stream>>>(spw,  spw_h,  256, 262144);
  wpackg_k<<<1024,256,0,stream>>>(msgw, msgw_h, 256, 262144);

  conv1m_k<<<8192,256,0,stream>>>(patches, wp1, c1b, b1g, b1b, h1);
  // conv2: 8 waves (NW=1, MT=2), IMG=4, LDS 64KB
  convm_k<32,64,16,8,8,1,2,7,0,0><<<2048,512,0,stream>>>(h1, wp2, c2b, b2g, b2b, h2, nullptr);
  // conv3: 4 waves = 2m x 2n, MT=2 -> IMG=4, LDS 32KB, NT/wave=4
  convm_k<64,128,8,4,4,2,2,8,11,0><<<2048,256,0,stream>>>(h2, wp3, c3b, b3g, b3b, h3, nullptr);
  // conv4: 8 waves = 2m x 4n, MT=2 -> IMG=16, LDS 64KB, NT/wave=4, fused pool
  convm_k<128,256,4,2,8,4,2,9,12,1><<<512,512,0,stream>>>(h3, wp4, c4b, b4g, b4b, nullptr, pooled);

  dim3 gg(128,4);
  gemm_m<0><<<gg,256,0,stream>>>(pooled, encw_h, encb, nullptr,nullptr,nullptr,
                                 nullptr,nullptr,nullptr, nullptr, imgf_h);
  gemm_m<1><<<gg,256,0,stream>>>(imgf_h, pjw_h, pjb, nullptr,nullptr,nullptr,
                                 nullptr, coords, pjw, tbuf, nullptr);
  ln_k<0><<<8192,256,0,stream>>>(tbuf, tbuf, plng, plnb, xa, xh);

  degcount_k<<<512,256,0,stream>>>(eidx+E_, deg);
  scan_k<<<1,256,0,stream>>>(deg, rowp, invd);
  fill_k<<<512,256,0,stream>>>(eidx, eidx+E_, rowp, curs, col);

  float* xcur = xa;
  for (int i=0;i<4;++i){
    gather_k<<<8192,256,0,stream>>>(xcur, rowp, col, invd, xbarh);
    gemm_m<2><<<gg,256,0,stream>>>(xh, spw_h+(size_t)i*65536, spb+(size_t)i*256,
                                   xbarh, msgw_h+(size_t)i*65536, msgb+(size_t)i*256,
                                   deg, nullptr, nullptr, tbuf, nullptr);
    float* xnext = (i==3)? out : ((i&1)? xa : xb);
    ln_k<1><<<8192,256,0,stream>>>(xcur, tbuf, lng+(size_t)i*256, lnb+(size_t)i*256, xnext, xh);
    xcur = xnext;
  }
  heads_k<<<8192,64,0,stream>>>(out, compw, compb, cmpow, cmpob, progw, progb, out);
}